// Round 1
// baseline (211.259 us; speedup 1.0000x reference)
//
#include <hip/hip_runtime.h>

#pragma clang fp contract(off)

#define H_ 192
#define W_ 192
#define HW_ (192 * 192)
#define NSC 3
#define NCAND (NSC * HW_)
#define CCH 256
#define KMAX 2048

// d_out layout (floats), in reference return order:
// keypoints [2048,2], descriptors [2048,256], scores [2048], det0/1/2 [192,192]
#define KP_OFF 0
#define DESC_OFF (KMAX * 2)
#define SC_OFF (DESC_OFF + KMAX * CCH)
#define DET_OFF (SC_OFF + KMAX)

typedef unsigned long long u64;
typedef unsigned int u32;

// ws layout (bytes):
//       0 : fin keys  u64[NCAND]   (884736 B, worst-case capacity)
//  884736 : nfin      u32 (+pad to 64 B)
//  884800 : selbuf    u64[KMAX]    (16384 B)

// Exact replica of the reference per-pixel math (NMS + handcrafted Newton
// localization). FP contraction is OFF for this TU so float ops match numpy
// bit-for-bit; tap order matches the conv's flattened tap order (zero taps
// are exact no-ops).
__device__ __forceinline__ void newton_pixel(const float* __restrict__ sm, int i, int j,
                                             float& det, float& ki, float& kj, bool& valid) {
    float v[3][3];
    float mx = -INFINITY;
#pragma unroll
    for (int a = 0; a < 3; ++a) {
#pragma unroll
        for (int b = 0; b < 3; ++b) {
            int ii = i + a - 1, jj = j + b - 1;
            bool in = (ii >= 0) && (ii < H_) && (jj >= 0) && (jj < W_);
            float val = in ? sm[ii * W_ + jj] : 0.0f;
            v[a][b] = val;
            if (in) mx = fmaxf(mx, val);
        }
    }
    float c = v[1][1];
    det = (mx == c) ? c : 0.0f;
    float di  = -0.5f * v[0][1] + 0.5f * v[2][1];
    float dj  = -0.5f * v[1][0] + 0.5f * v[1][2];
    float dii = v[0][1] - 2.0f * c + v[2][1];
    float djj = v[1][0] - 2.0f * c + v[1][2];
    float dij = 0.25f * v[0][0] - 0.25f * v[0][2] - 0.25f * v[2][0] + 0.25f * v[2][2];
    float dd = dii * djj - dij * dij;
    if (dd == 0.0f) dd = 1e-20f;
    float step_i = -(djj * di - dij * dj) / dd;
    float step_j = -(-dij * di + dii * dj) / dd;
    valid = (det != 0.0f) && (fabsf(step_i) < 0.5f) && (fabsf(step_j) < 0.5f);
    ki = valid ? ((float)i + step_i) : 0.0f;
    kj = valid ? ((float)j + step_j) : 0.0f;
    float i0 = floorf(ki), j0 = floorf(kj);
    valid = valid && (i0 >= 0.0f) && (j0 >= 0.0f) &&
            (i0 + 1.0f <= (float)(H_ - 1)) && (j0 + 1.0f <= (float)(W_ - 1));
}

// Kernel 1: per-pixel NMS/Newton; write det maps; append valid candidate keys
// (block-aggregated atomic append; order irrelevant, sorted later).
__global__ __launch_bounds__(256) void cand_kernel(
    const float* __restrict__ s0, const float* __restrict__ s1, const float* __restrict__ s2,
    float* __restrict__ out, u64* __restrict__ fin, u32* __restrict__ nfin) {
    __shared__ u32 lcnt, base;
    if (threadIdx.x == 0) lcnt = 0;
    __syncthreads();
    int t = blockIdx.x * 256 + threadIdx.x;
    bool valid = false;
    u64 key = 0;
    if (t < NCAND) {
        int s = t / HW_;
        int rem = t - s * HW_;
        int i = rem / W_;
        int j = rem - i * W_;
        const float* sm = (s == 0) ? s0 : (s == 1) ? s1 : s2;
        float det, ki, kj;
        newton_pixel(sm, i, j, det, ki, kj, valid);
        out[DET_OFF + t] = det;
        if (valid) {
            // det > 0 here; ordered-float of a positive value = bits | 0x80000000.
            u32 sb = __float_as_uint(det) | 0x80000000u;
            key = ((u64)sb << 32) | (u64)(0xFFFFFFFFu - (u32)t);  // ties -> lower idx first
        }
    }
    u32 lpos = 0;
    if (valid) lpos = atomicAdd(&lcnt, 1u);
    __syncthreads();
    if (threadIdx.x == 0 && lcnt > 0) base = atomicAdd(nfin, lcnt);
    __syncthreads();
    if (valid) fin[base + lpos] = key;
}

// Kernel 2 (single block, 1024 threads): exact radix-select of the 2048th
// largest 64-bit key (keys unique -> exactly 2048 survivors), compact into
// LDS, bitonic sort descending, write sorted list.
__global__ __launch_bounds__(1024) void select_sort_kernel(
    const u64* __restrict__ fin, const u32* __restrict__ nfin, u64* __restrict__ selbuf) {
    __shared__ u32 h[256];
    __shared__ u64 sh_prefix;
    __shared__ u32 sh_K;
    __shared__ u32 cnt;
    __shared__ u64 a[KMAX];
    int tid = threadIdx.x;
    u32 n = *nfin;
    u64 kth = 0;  // n <= 2048: take everything
    if (n > KMAX) {
        if (tid == 0) { sh_prefix = 0ull; sh_K = KMAX; }
        for (int p = 0; p < 8; ++p) {
            if (tid < 256) h[tid] = 0;
            __syncthreads();
            u64 prefix = sh_prefix;
            u32 K = sh_K;
            int shift = 56 - 8 * p;
            for (u32 idx = tid; idx < n; idx += 1024) {
                u64 key = fin[idx];
                bool match = (p == 0) || ((key >> (shift + 8)) == (prefix >> (shift + 8)));
                if (match) atomicAdd(&h[(u32)(key >> shift) & 255u], 1u);
            }
            __syncthreads();
            // suffix sums: h[d] = count of matching keys with digit >= d
            for (int off = 1; off < 256; off <<= 1) {
                u32 tv = 0;
                if (tid < 256 && tid + off < 256) tv = h[tid + off];
                __syncthreads();
                if (tid < 256) h[tid] += tv;
                __syncthreads();
            }
            if (tid < 256) {
                u32 ge = h[tid];
                u32 gt = (tid < 255) ? h[tid + 1] : 0u;
                if (ge >= K && gt < K) {
                    sh_prefix = prefix | (((u64)(u32)tid) << shift);
                    sh_K = K - gt;
                }
            }
            __syncthreads();
        }
        kth = sh_prefix;  // exact value of the 2048th-largest key
    }
    if (tid == 0) cnt = 0;
    __syncthreads();
    for (u32 idx = tid; idx < n; idx += 1024) {
        u64 key = fin[idx];
        if (key >= kth) {
            u32 pos = atomicAdd(&cnt, 1u);
            if (pos < KMAX) a[pos] = key;
        }
    }
    __syncthreads();
    u32 m = cnt;
    if (m > KMAX) m = KMAX;
    for (u32 idx = tid; idx < KMAX; idx += 1024)
        if (idx >= m) a[idx] = 0ull;  // padding: sorts last, emits zero rows
    __syncthreads();
    // bitonic sort, descending
    for (u32 k = 2; k <= KMAX; k <<= 1) {
        for (u32 jj = k >> 1; jj > 0; jj >>= 1) {
            for (u32 idx = tid; idx < KMAX; idx += 1024) {
                u32 ixj = idx ^ jj;
                if (ixj > idx) {
                    u64 x = a[idx], y = a[ixj];
                    bool descSeg = ((idx & k) == 0);
                    bool doswap = descSeg ? (x < y) : (x > y);
                    if (doswap) { a[idx] = y; a[ixj] = x; }
                }
            }
            __syncthreads();
        }
    }
    for (u32 idx = tid; idx < KMAX; idx += 1024) selbuf[idx] = a[idx];
}

// Kernel 3: one block (256 threads = 256 channels) per output slot.
// Recompute ki/kj for the winner pixel, bilinear-interp 256-ch descriptor,
// L2-normalize, emit keypoint/score. Invalid / padded slots -> zeros.
__global__ __launch_bounds__(256) void output_kernel(
    const u64* __restrict__ selbuf,
    const float* __restrict__ f0, const float* __restrict__ f1, const float* __restrict__ f2,
    const float* __restrict__ s0, const float* __restrict__ s1, const float* __restrict__ s2,
    float* __restrict__ out) {
    __shared__ float red[256];
    int r = blockIdx.x;
    int tid = threadIdx.x;
    u64 key = selbuf[r];
    u32 hi = (u32)(key >> 32);
    if (hi < 0x80000001u) {  // padding (0) — no finite det>0 key here
        out[DESC_OFF + r * CCH + tid] = 0.0f;
        if (tid == 0) {
            out[SC_OFF + r] = 0.0f;
            out[KP_OFF + r * 2 + 0] = 0.0f;
            out[KP_OFF + r * 2 + 1] = 0.0f;
        }
        return;
    }
    u32 gid = 0xFFFFFFFFu - (u32)(key & 0xFFFFFFFFull);
    int s = gid / HW_;
    int rem = gid - s * HW_;
    int i = rem / W_;
    int j = rem - i * W_;
    const float* sm = (s == 0) ? s0 : (s == 1) ? s1 : s2;
    const float* feat = (s == 0) ? f0 : (s == 1) ? f1 : f2;
    float det, ki, kj;
    bool valid;
    newton_pixel(sm, i, j, det, ki, kj, valid);  // valid guaranteed true here
    int i0 = (int)floorf(ki), j0 = (int)floorf(kj);
    float wi = ki - (float)i0;
    float wj = kj - (float)j0;
    const float* p = feat + (size_t)tid * HW_ + i0 * W_ + j0;
    float f00 = p[0], f01 = p[1], f10 = p[W_], f11 = p[W_ + 1];
    float d = f00 * (1.0f - wi) * (1.0f - wj) + f01 * (1.0f - wi) * wj +
              f10 * wi * (1.0f - wj) + f11 * wi * wj;
    red[tid] = d * d;
    __syncthreads();
    for (int st = 128; st > 0; st >>= 1) {
        if (tid < st) red[tid] += red[tid + st];
        __syncthreads();
    }
    float norm = fmaxf(sqrtf(red[0]), 1e-12f);
    out[DESC_OFF + r * CCH + tid] = d / norm;
    if (tid == 0) {
        out[SC_OFF + r] = __uint_as_float(hi & 0x7FFFFFFFu);  // invert ordered-float (positive)
        float x = kj, y = ki;
#pragma unroll
        for (int u = 0; u < 4; ++u) { x = x * 2.0f + 0.5f; y = y * 2.0f + 0.5f; }
        out[KP_OFF + r * 2 + 0] = x;  // (x=col, y=row) per reference [:, [1,0]] swap
        out[KP_OFF + r * 2 + 1] = y;
    }
}

extern "C" void kernel_launch(void* const* d_in, const int* in_sizes, int n_in,
                              void* d_out, int out_size, void* d_ws, size_t ws_size,
                              hipStream_t stream) {
    const float* f0 = (const float*)d_in[0];
    const float* f1 = (const float*)d_in[1];
    const float* f2 = (const float*)d_in[2];
    const float* s0 = (const float*)d_in[3];
    const float* s1 = (const float*)d_in[4];
    const float* s2 = (const float*)d_in[5];
    float* out = (float*)d_out;

    char* ws = (char*)d_ws;
    u64* fin = (u64*)ws;                     // 884736 B
    u32* nfin = (u32*)(ws + 884736);         // 64 B (counter + pad)
    u64* selbuf = (u64*)(ws + 884800);       // 16384 B

    hipMemsetAsync(nfin, 0, 64, stream);
    cand_kernel<<<NCAND / 256, 256, 0, stream>>>(s0, s1, s2, out, fin, nfin);
    select_sort_kernel<<<1, 1024, 0, stream>>>(fin, nfin, selbuf);
    output_kernel<<<KMAX, 256, 0, stream>>>(selbuf, f0, f1, f2, s0, s1, s2, out);
}